// Round 3
// baseline (1943.807 us; speedup 1.0000x reference)
//
#include <hip/hip_runtime.h>

// ---------------------------------------------------------------------------
// BlockLSTM forward, MI355X (gfx950).  T=512, B=64, I=U=512.
// out = [h_seq (T,B,U) | final_cs (B,U) | final_h (B,U)] fp32
//
// z-columns permuted unit-major: col' = u*4 + g  (orig col = g*512 + u).
// zxp stored in MFMA 32x32 C-fragment order (unchanged gemm epilogue).
//
// hbf layout (NEW): [t][rowgroup g(8)][unit-chunk c8(64)][r8(8)][8 units-PERM]
//   elem = t*32768 + g*4096 + c8*64 + r8*8 + uw(u&7),  uw(u) = (u&3)*2+(u>>2)
//   (intra-8 unit order [0,4,1,5,2,6,3,7]; wT's k-axis for k>=512 permuted
//    identically so MFMA K-dims match. Makes each producer lane's two units
//    dword-adjacent -> one 4B store, dword-granular poison stays sound.)
//
// SYNC: data-is-flag (bf16 NaN 0x7FC0 poison; h=tanh*sigmoid never NaN).
// NEW: XCD-local rendezvous. Rowgroup g == bid&7 == (empirical) XCD id.
// Producers DUAL-store h: normal store (lands in own XCD L2) + agent store
// (MALL master). Consumers poll with SE-scope loads (sc0: bypass L1, hit
// L2). If local polling doesn't validate in a few tries (placement broken,
// whatever), fall back to agent loads from the master -> correct regardless
// of workgroup->XCD assignment (G16); fast path is a ~200cy L2 hit instead
// of a ~600cy MALL round-trip.
//
// MFMA orientation SWAPPED vs before: z^T = (wT-frag) x (h-frag), so D has
// lane = batch row, regs = the 4 gates of one unit -> NO LDS transpose at
// all; gates read acc regs directly. zx added as scalars at gate time.
//
// Recurrence: 512 blocks x 64 thr. Block (g=bid&7, cb=bid>>3): rows
// [g*8,+8), units [cb*8,+8). Rows duplicated across lane halves (latency-
// bound; redundant FLOPs free). 2 blocks/CU.
//
// ws layout (~164.1 MB):
//   [0,   4MB)        wT   bf16 [2048 permuted cols][1024 k (k>=512 perm)]
//   [4MB, 132MB)      zxp  bf16 [512][64][2][64][16]
//   [132MB, +32.07MB) hbf  bf16 [513 slots][32768]  (slot t = h_{t-1})
// ---------------------------------------------------------------------------

#define T_STEPS 512
#define NB 64
#define NU 512
#define NI 512
#define KTOT 1024
#define ZCOLS 2048
#define HSEQ_ELEMS (T_STEPS * NB * NU)
#define POISON64 0x7FC07FC07FC07FC0ull

typedef float    floatx4   __attribute__((ext_vector_type(4)));
typedef __bf16   bf16x8    __attribute__((ext_vector_type(8)));
typedef unsigned short ushortx8 __attribute__((ext_vector_type(8)));
typedef unsigned long long ull_t;

static __device__ __forceinline__ unsigned short f2bf(float f) {
  unsigned int u = __builtin_bit_cast(unsigned int, f);
  u += 0x7fffu + ((u >> 16) & 1u);  // RNE
  return (unsigned short)(u >> 16);
}
static __device__ __forceinline__ float bf2f(unsigned short h) {
  unsigned int u = ((unsigned int)h) << 16;
  return __builtin_bit_cast(float, u);
}
static __device__ __forceinline__ float sigmoidf_(float x) {
  return __builtin_amdgcn_rcpf(1.0f + __expf(-x));
}
static __device__ __forceinline__ float fast_tanhf(float x) {
  const float ax = fabsf(x);
  const float t = __expf(-2.0f * ax);
  const float r = (1.0f - t) * __builtin_amdgcn_rcpf(1.0f + t);
  return copysignf(r, x);
}
static __device__ __forceinline__ bf16x8 ldfrag(const unsigned short* p) {
  ushortx8 v = *reinterpret_cast<const ushortx8*>(p);
  return __builtin_bit_cast(bf16x8, v);
}
static __device__ __forceinline__ ull_t pack4bf(float a, float b, float c, float d) {
  return (ull_t)f2bf(a) | ((ull_t)f2bf(b) << 16) | ((ull_t)f2bf(c) << 32) |
         ((ull_t)f2bf(d) << 48);
}
// 16B load bypassing L1+L2 (agent-coherent read from MALL).
static __device__ __forceinline__ floatx4 ld_agent16f(const unsigned short* p) {
  ull_t lo = __hip_atomic_load((const ull_t*)p, __ATOMIC_RELAXED, __HIP_MEMORY_SCOPE_AGENT);
  ull_t hi = __hip_atomic_load((const ull_t*)(p + 4), __ATOMIC_RELAXED, __HIP_MEMORY_SCOPE_AGENT);
  struct P { ull_t a, b; } s{lo, hi};
  return __builtin_bit_cast(floatx4, s);
}

// ---------------------------------------------------------------------------
// init: poison hbf slots 1..512; slot0 = bf16(h0) in PERMUTED chunk order.
// grid 2056 x 256.
// ---------------------------------------------------------------------------
__global__ __launch_bounds__(256) void init_kernel(const float* __restrict__ h0,
                                                   unsigned short* __restrict__ hbf) {
  const int j = blockIdx.x * 256 + threadIdx.x;  // 0..526335
  if (j < 524288) {
    ull_t* p = reinterpret_cast<ull_t*>(&hbf[32768 + (size_t)j * 32]);
#pragma unroll
    for (int r = 0; r < 8; ++r) p[r] = POISON64;
  } else {
    const int k = j - 524288;  // 0..2047
#pragma unroll
    for (int p2 = 0; p2 < 2; ++p2) {
      const int i = k * 2 + p2;  // 0..4095
      const int row = i >> 6, chunk = i & 63;
      const float* src = &h0[row * NU + chunk * 8];
      // permuted intra-8 order [0,4,1,5,2,6,3,7]
      const ull_t lo = pack4bf(src[0], src[4], src[1], src[5]);
      const ull_t hi = pack4bf(src[2], src[6], src[3], src[7]);
      const size_t off =
          (size_t)(row >> 3) * 4096 + (size_t)chunk * 64 + (size_t)(row & 7) * 8;
      *reinterpret_cast<ull_t*>(&hbf[off]) = lo;
      *reinterpret_cast<ull_t*>(&hbf[off + 4]) = hi;
    }
  }
}

// ---------------------------------------------------------------------------
// transpose + permute: wT[(u*4+g)][k'] = bf16(w[k][g*512+u]);
// k' = k for k<512, intra-8 permuted (uw) for k>=512 (matches hbf order).
// ---------------------------------------------------------------------------
__global__ __launch_bounds__(256) void transpose_w_kernel(
    const float* __restrict__ w, unsigned short* __restrict__ wT) {
  __shared__ float tile[32][33];
  const int u0 = blockIdx.x * 32;
  const int k0 = blockIdx.y * 32;
  const int g = blockIdx.z;
  const int tx = threadIdx.x & 31, ty = threadIdx.x >> 5;
#pragma unroll
  for (int r = 0; r < 4; ++r) {
    const int k = ty + r * 8;
    tile[k][tx] = w[(size_t)(k0 + k) * ZCOLS + g * 512 + u0 + tx];
  }
  __syncthreads();
#pragma unroll
  for (int r = 0; r < 4; ++r) {
    const int u = ty + r * 8;
    const int kk = k0 + tx;
    int kd = kk;
    if (kk >= 512) {
      const int u3 = kk & 7;
      kd = (kk & ~7) | (((u3 & 3) << 1) | (u3 >> 2));
    }
    wT[(size_t)((u0 + u) * 4 + g) * KTOT + kd] = f2bf(tile[tx][u]);
  }
}

// ---------------------------------------------------------------------------
// gemm: zxp = (x @ wx + b) in permuted cols, 32x32 C-fragment order.
// (uses wT k<512 only -> unaffected by the k>=512 permutation)
// ---------------------------------------------------------------------------
__global__ __launch_bounds__(256) void gemm_zx_kernel(
    const float* __restrict__ x, const unsigned short* __restrict__ wT,
    const float* __restrict__ bias, unsigned short* __restrict__ zxp) {
  __shared__ __align__(16) unsigned short As[128][32];
  __shared__ __align__(16) unsigned short Bs[128][32];
  const int m0 = blockIdx.y * 128;
  const int n0 = blockIdx.x * 128;
  const int tid = threadIdx.x;
  const int wid = tid >> 6, lane = tid & 63;
  const int quad = lane >> 4, nl = lane & 15;
  const int wm = (wid & 1) * 64, wn = (wid >> 1) * 64;
  const int srow = tid >> 3;
  const int skk = (tid & 7) * 4;

  floatx4 acc[4][4] = {};

  for (int kt = 0; kt < 16; ++kt) {
    const int k0 = kt * 32;
    __syncthreads();
#pragma unroll
    for (int r = 0; r < 4; ++r) {
      const int row = r * 32 + srow;
      const float4 v =
          *reinterpret_cast<const float4*>(&x[(size_t)(m0 + row) * NI + k0 + skk]);
      *reinterpret_cast<ull_t*>(&As[row][skk]) = pack4bf(v.x, v.y, v.z, v.w);
      *reinterpret_cast<ull_t*>(&Bs[row][skk]) =
          *reinterpret_cast<const ull_t*>(&wT[(size_t)(n0 + row) * KTOT + k0 + skk]);
    }
    __syncthreads();
    bf16x8 af[4], bfr[4];
#pragma unroll
    for (int i = 0; i < 4; ++i) {
      af[i] = ldfrag(&As[wm + i * 16 + nl][quad * 8]);
      bfr[i] = ldfrag(&Bs[wn + i * 16 + nl][quad * 8]);
    }
#pragma unroll
    for (int i = 0; i < 4; ++i)
#pragma unroll
      for (int j = 0; j < 4; ++j)
        acc[i][j] =
            __builtin_amdgcn_mfma_f32_16x16x32_bf16(af[i], bfr[j], acc[i][j], 0, 0, 0);
  }

  float bv[4];
#pragma unroll
  for (int j = 0; j < 4; ++j) {
    const int colp = n0 + wn + j * 16 + nl;
    bv[j] = bias[(colp & 3) * 512 + (colp >> 2)];
  }
#pragma unroll
  for (int i = 0; i < 4; ++i) {
    const int browb = wm + i * 16 + quad * 4;
    const int t = (m0 + browb) >> 6;
    const int rt = (browb >> 5) & 1;
    const int hi = (browb & 31) >> 3;
    const int qb = (browb >> 2) & 1;
#pragma unroll
    for (int j = 0; j < 4; ++j) {
      const int colp = n0 + wn + j * 16 + nl;
      const int cbl = colp >> 5;
      const int lanep = (colp & 31) + 32 * qb;
      const ull_t packed =
          pack4bf(acc[i][j][0] + bv[j], acc[i][j][1] + bv[j],
                  acc[i][j][2] + bv[j], acc[i][j][3] + bv[j]);
      *reinterpret_cast<ull_t*>(
          &zxp[((((size_t)t * 64 + cbl) * 2 + rt) * 64 + lanep) * 16 + hi * 4]) = packed;
    }
  }
}

// ---------------------------------------------------------------------------
// recurrence: 512 blocks x 64 thr. g = bid&7 (rowgroup == assumed XCD),
// cb = bid>>3 (units [cb*8,+8)). Swapped MFMA (lane = row, regs = gates).
// XCD-local L2 rendezvous + agent master fallback.
// ---------------------------------------------------------------------------
__global__ __launch_bounds__(64) void lstm_rec_kernel(
    const unsigned short* __restrict__ zxp, const unsigned short* __restrict__ wT,
    const float* __restrict__ cs_init, float* __restrict__ out,
    unsigned short* __restrict__ hbf) {
  const int lane = threadIdx.x;
  const int bid = blockIdx.x;
  const int g = bid & 7;                 // rowgroup; rows [g*8, +8)
  const int cb = bid >> 3;               // units [cb*8, +8)
  const int l15 = lane & 15, lq = lane >> 4;
  const int r8 = l15 & 7;                // lanes l15>=8 duplicate rows (free)
  const int rowg = g * 8 + r8;

  // A-operand resident: wT frags; lane m-index = l15 -> zcol cb*32+cf*16+l15
  bf16x8 Bf[2][16];
#pragma unroll
  for (int cf = 0; cf < 2; ++cf)
#pragma unroll
    for (int kf = 0; kf < 16; ++kf)
      Bf[cf][kf] = ldfrag(
          &wT[(size_t)(cb * 32 + cf * 16 + l15) * KTOT + 512 + kf * 32 + lq * 8]);

  // cell state: (row rowg, units cb*8+lq and cb*8+4+lq)
  float csv[2];
  csv[0] = cs_init[rowg * NU + cb * 8 + lq];
  csv[1] = cs_init[rowg * NU + cb * 8 + 4 + lq];

  floatx4 Af[16];          // h fragments (B-operand), also validation view
  unsigned short zxv[8];   // zx gate values (cf*4 + r)

  // SE-scope (sc0: bypass L1, hit local-XCD L2) speculative fragment loads
  auto issueL = [&](int tt) {
    const unsigned short* p0 =
        hbf + (size_t)tt * 32768 + g * 4096 + lq * 64 + r8 * 8;
#pragma unroll
    for (int kf = 0; kf < 16; ++kf) {
      asm volatile("global_load_dwordx4 %0, %1, off sc0"
                   : "=v"(Af[kf])
                   : "v"(p0 + (size_t)kf * 256)
                   : "memory");
    }
  };
  // agent-scope (MALL master) loads
  auto issueM = [&](int tt) {
    const unsigned short* p0 =
        hbf + (size_t)tt * 32768 + g * 4096 + lq * 64 + r8 * 8;
#pragma unroll
    for (int kf = 0; kf < 16; ++kf) Af[kf] = ld_agent16f(p0 + (size_t)kf * 256);
  };
  // zx scalar preloads (C-fragment layout of gemm epilogue)
  const int rt_ = rowg >> 5;
  const int qb_ = (rowg >> 2) & 1;
  const int hi_ = (rowg & 31) >> 3;
  const int rr_ = rowg & 3;
  auto issueZ = [&](int tt) {
    const size_t base = (((size_t)tt * 64 + cb) * 2 + rt_) * 64;
#pragma unroll
    for (int cf = 0; cf < 2; ++cf)
#pragma unroll
      for (int r = 0; r < 4; ++r) {
        const int c5 = cf * 16 + lq * 4 + r;
        zxv[cf * 4 + r] = zxp[(base + (size_t)(c5 + 32 * qb_)) * 16 + hi_ * 4 + rr_];
      }
  };

  issueL(0);
  issueZ(0);

  int mstreak = 0;
  bool preferM = false;

  for (int t = 0; t < T_STEPS; ++t) {
    // ---- poll: validate pre-issued frags; local retries then master ----
    bool usedM = false;
    int tries = 0;
    while (true) {
      asm volatile("s_waitcnt vmcnt(0)" ::: "memory");
      __builtin_amdgcn_sched_barrier(0);
      floatx4 vs = Af[0];
#pragma unroll
      for (int kf = 1; kf < 16; ++kf) vs += Af[kf];
      const float s = (vs[0] + vs[1]) + (vs[2] + vs[3]);
      if (!__any(s != s)) break;          // no poison dword anywhere in wave
      if (++tries >= (1 << 18)) break;    // safety: never hang
      if (!preferM && tries < 4) {
        issueL(t);
      } else {
        usedM = true;
        issueM(t);
      }
    }
    if (usedM) {
      if (++mstreak > 8) preferM = true;  // placement broken: go master-first
    } else {
      mstreak = 0;
    }

    // ---- z^T = wT x h : 4 chains of 8; D lane = row, regs = gates ----
    floatx4 p00 = {0.f, 0.f, 0.f, 0.f}, p01 = {0.f, 0.f, 0.f, 0.f};
    floatx4 p10 = {0.f, 0.f, 0.f, 0.f}, p11 = {0.f, 0.f, 0.f, 0.f};
#pragma unroll
    for (int kf = 0; kf < 8; ++kf) {
      const bf16x8 hlo = __builtin_bit_cast(bf16x8, Af[kf]);
      const bf16x8 hhi = __builtin_bit_cast(bf16x8, Af[8 + kf]);
      p00 = __builtin_amdgcn_mfma_f32_16x16x32_bf16(Bf[0][kf], hlo, p00, 0, 0, 0);
      p01 = __builtin_amdgcn_mfma_f32_16x16x32_bf16(Bf[1][kf], hlo, p01, 0, 0, 0);
      p10 = __builtin_amdgcn_mfma_f32_16x16x32_bf16(Bf[0][8 + kf], hhi, p10, 0, 0, 0);
      p11 = __builtin_amdgcn_mfma_f32_16x16x32_bf16(Bf[1][8 + kf], hhi, p11, 0, 0, 0);
    }
    const floatx4 z0 = p00 + p10;  // unit cb*8+lq     : gates (i,ci,f,o)
    const floatx4 z1 = p01 + p11;  // unit cb*8+4+lq   : gates (i,ci,f,o)

    // ---- gates directly on acc regs + zx scalars ----
    float hout[2];
    {
      const float iv = sigmoidf_(z0[0] + bf2f(zxv[0]));
      const float civ = fast_tanhf(z0[1] + bf2f(zxv[1]));
      const float fv = sigmoidf_(z0[2] + bf2f(zxv[2]) + 1.0f);  // forget_bias
      const float ov = sigmoidf_(z0[3] + bf2f(zxv[3]));
      csv[0] = civ * iv + csv[0] * fv;
      hout[0] = fast_tanhf(csv[0]) * ov;
    }
    {
      const float iv = sigmoidf_(z1[0] + bf2f(zxv[4]));
      const float civ = fast_tanhf(z1[1] + bf2f(zxv[5]));
      const float fv = sigmoidf_(z1[2] + bf2f(zxv[6]) + 1.0f);
      const float ov = sigmoidf_(z1[3] + bf2f(zxv[7]));
      csv[1] = civ * iv + csv[1] * fv;
      hout[1] = fast_tanhf(csv[1]) * ov;
    }

    // ---- h dual-store: local XCD L2 (normal) + MALL master (agent) ----
    const unsigned hv =
        (unsigned)f2bf(hout[0]) | ((unsigned)f2bf(hout[1]) << 16);
    unsigned short* hw = &hbf[(size_t)(t + 1) * 32768 + g * 4096 + cb * 64 +
                              r8 * 8 + 2 * lq];
    if (l15 < 8) {
      *(volatile unsigned*)hw = hv;  // -> own L2 (write-through L1)
      __hip_atomic_store(reinterpret_cast<unsigned*>(hw), hv, __ATOMIC_RELAXED,
                         __HIP_MEMORY_SCOPE_AGENT);  // -> MALL
    }

    // ---- pre-issue next step's poll (overlaps everything below) ----
    if (t + 1 < T_STEPS) {
      if (!preferM) issueL(t + 1);
      else          issueM(t + 1);
      issueZ(t + 1);
    }

    // ---- out stores (off the critical path) ----
    if (l15 < 8) {
      float* op = &out[((size_t)t * NB + rowg) * NU + cb * 8];
      op[lq] = hout[0];
      op[4 + lq] = hout[1];
      if (t == T_STEPS - 1) {
        float* cp = &out[HSEQ_ELEMS + (size_t)rowg * NU + cb * 8];
        cp[lq] = csv[0];
        cp[4 + lq] = csv[1];
        float* hp2 = &out[HSEQ_ELEMS + NB * NU + (size_t)rowg * NU + cb * 8];
        hp2[lq] = hout[0];
        hp2[4 + lq] = hout[1];
      }
    }
  }
}

// ---------------------------------------------------------------------------
extern "C" void kernel_launch(void* const* d_in, const int* in_sizes, int n_in,
                              void* d_out, int out_size, void* d_ws, size_t ws_size,
                              hipStream_t stream) {
  const float* x = (const float*)d_in[0];
  const float* cs0 = (const float*)d_in[1];
  const float* h0 = (const float*)d_in[2];
  const float* w = (const float*)d_in[3];
  const float* bias = (const float*)d_in[4];
  float* out = (float*)d_out;

  char* ws = (char*)d_ws;
  unsigned short* wT = (unsigned short*)(ws);
  unsigned short* zxp = (unsigned short*)(ws + (size_t)(4 << 20));
  unsigned short* hbf = (unsigned short*)(ws + (size_t)(132 << 20));

  init_kernel<<<dim3(2056), 256, 0, stream>>>(h0, hbf);
  transpose_w_kernel<<<dim3(16, 32, 4), 256, 0, stream>>>(w, wT);
  gemm_zx_kernel<<<dim3(16, 256), 256, 0, stream>>>(x, wT, bias, zxp);
  lstm_rec_kernel<<<dim3(512), 64, 0, stream>>>(zxp, wT, cs0, out, hbf);
}

// Round 4
// 1305.239 us; speedup vs baseline: 1.4892x; 1.4892x over previous
//
#include <hip/hip_runtime.h>

// ---------------------------------------------------------------------------
// BlockLSTM forward, MI355X (gfx950).  T=512, B=64, I=U=512.
// out = [h_seq (T,B,U) | final_cs (B,U) | final_h (B,U)] fp32
//
// z-columns permuted unit-major: col' = u*4 + g  (orig col = g*512 + u).
// zxp stored in MFMA 32x32 C-fragment order (unchanged gemm epilogue).
//
// hbf layout: [t][kf(16)][quadc(4)][row(64)][8 units PERM]  bf16
//   elem = t*32768 + kf*2048 + quadc*512 + row*8 + idx
//   unit at idx = kf*32 + quadc*8 + perm[idx], perm = [0,4,1,5,2,6,3,7]
//   (wT's k-axis for k>=512 permuted identically so MFMA K-slots match.
//    Producer lane's two units (u, u+4) land dword-adjacent -> one 4B store;
//    poison detection stays dword-granular and tear-free.)
//
// SYNC: data-is-flag (bf16 NaN 0x7FC0 poison; h = tanh*sigmoid never NaN).
// NEW (this version): SPECULATIVE MFMA. Consumers run the MFMA chain directly
// on speculatively-loaded h fragments and validate the 8 accumulated z values
// for NaN (poison propagates bf16->f32 acc). Steady case: zero validation
// cost before compute; retry = reload + redo 32 MFMAs (~160cy). All hbf
// polling via __hip_atomic_load (compiler-precise waitcnts; no vmcnt(0)
// that would wait on store acks -- R3's mistake).
//
// MFMA orientation swapped: z^T = (wT-frag) x (h-frag): lane l15 = batch row
// (16 rows = one qr group, NO row duplication), acc regs = 4 gates of one
// unit. No LDS anywhere in the rec kernel.
//
// Recurrence: 256 blocks x 64 thr (1 wave). Block (cb=bid>>2, qr=bid&3):
// units [cb*8,+8), rows [qr*16,+16). 1 wave/CU.
//
// ws layout (~164.1 MB):
//   [0,   4MB)        wT   bf16 [2048 permuted cols][1024 k (k>=512 perm)]
//   [4MB, 132MB)      zxp  bf16 [512][64][2][64][16]
//   [132MB, +32.06MB) hbf  bf16 [513 slots][32768]  (slot t = h_{t-1})
// ---------------------------------------------------------------------------

#define T_STEPS 512
#define NB 64
#define NU 512
#define NI 512
#define KTOT 1024
#define ZCOLS 2048
#define HSEQ_ELEMS (T_STEPS * NB * NU)
#define POISON64 0x7FC07FC07FC07FC0ull

typedef float    floatx4   __attribute__((ext_vector_type(4)));
typedef __bf16   bf16x8    __attribute__((ext_vector_type(8)));
typedef unsigned short ushortx8 __attribute__((ext_vector_type(8)));
typedef unsigned long long ull_t;

static __device__ __forceinline__ unsigned short f2bf(float f) {
  unsigned int u = __builtin_bit_cast(unsigned int, f);
  u += 0x7fffu + ((u >> 16) & 1u);  // RNE
  return (unsigned short)(u >> 16);
}
static __device__ __forceinline__ float bf2f(unsigned short h) {
  unsigned int u = ((unsigned int)h) << 16;
  return __builtin_bit_cast(float, u);
}
static __device__ __forceinline__ float sigmoidf_(float x) {
  return __builtin_amdgcn_rcpf(1.0f + __expf(-x));
}
static __device__ __forceinline__ float fast_tanhf(float x) {
  const float ax = fabsf(x);
  const float t = __expf(-2.0f * ax);
  const float r = (1.0f - t) * __builtin_amdgcn_rcpf(1.0f + t);
  return copysignf(r, x);
}
static __device__ __forceinline__ bf16x8 ldfrag(const unsigned short* p) {
  ushortx8 v = *reinterpret_cast<const ushortx8*>(p);
  return __builtin_bit_cast(bf16x8, v);
}
static __device__ __forceinline__ ull_t pack4bf(float a, float b, float c, float d) {
  return (ull_t)f2bf(a) | ((ull_t)f2bf(b) << 16) | ((ull_t)f2bf(c) << 32) |
         ((ull_t)f2bf(d) << 48);
}
static __device__ __forceinline__ bf16x8 mkfrag(ull_t lo, ull_t hi) {
  struct P { ull_t a, b; } s{lo, hi};
  return __builtin_bit_cast(bf16x8, s);
}

// ---------------------------------------------------------------------------
// init: poison hbf slots 1..512; slot0 = bf16(h0) in frag layout (perm'd).
// grid 2056 x 256.
// ---------------------------------------------------------------------------
__global__ __launch_bounds__(256) void init_kernel(const float* __restrict__ h0,
                                                   unsigned short* __restrict__ hbf) {
  const int j = blockIdx.x * 256 + threadIdx.x;  // 0..526335
  if (j < 524288) {
    ull_t* p = reinterpret_cast<ull_t*>(&hbf[32768 + (size_t)j * 32]);
#pragma unroll
    for (int r = 0; r < 8; ++r) p[r] = POISON64;
  } else {
    const int k = j - 524288;  // 0..2047
#pragma unroll
    for (int p2 = 0; p2 < 2; ++p2) {
      const int i = k * 2 + p2;  // 0..4095
      const int row = i >> 6, chunk = i & 63;  // chunk = unit>>3
      const float* src = &h0[row * NU + chunk * 8];
      // perm [0,4,1,5,2,6,3,7]
      const ull_t lo = pack4bf(src[0], src[4], src[1], src[5]);
      const ull_t hi = pack4bf(src[2], src[6], src[3], src[7]);
      const size_t off =
          (size_t)(chunk >> 2) * 2048 + (size_t)(chunk & 3) * 512 + (size_t)row * 8;
      *reinterpret_cast<ull_t*>(&hbf[off]) = lo;
      *reinterpret_cast<ull_t*>(&hbf[off + 4]) = hi;
    }
  }
}

// ---------------------------------------------------------------------------
// transpose + permute: wT[(u*4+g)][k'] = bf16(w[k][g*512+u]);
// k' = k for k<512, intra-8 permuted for k>=512 (matches hbf frag order).
// ---------------------------------------------------------------------------
__global__ __launch_bounds__(256) void transpose_w_kernel(
    const float* __restrict__ w, unsigned short* __restrict__ wT) {
  __shared__ float tile[32][33];
  const int u0 = blockIdx.x * 32;
  const int k0 = blockIdx.y * 32;
  const int g = blockIdx.z;
  const int tx = threadIdx.x & 31, ty = threadIdx.x >> 5;
#pragma unroll
  for (int r = 0; r < 4; ++r) {
    const int k = ty + r * 8;
    tile[k][tx] = w[(size_t)(k0 + k) * ZCOLS + g * 512 + u0 + tx];
  }
  __syncthreads();
#pragma unroll
  for (int r = 0; r < 4; ++r) {
    const int u = ty + r * 8;
    const int kk = k0 + tx;
    int kd = kk;
    if (kk >= 512) {
      const int u3 = kk & 7;
      kd = (kk & ~7) | (((u3 & 3) << 1) | (u3 >> 2));
    }
    wT[(size_t)((u0 + u) * 4 + g) * KTOT + kd] = f2bf(tile[tx][u]);
  }
}

// ---------------------------------------------------------------------------
// gemm: zxp = (x @ wx + b) in permuted cols, 32x32 C-fragment order.
// (uses wT k<512 only -> unaffected by the k>=512 permutation)
// ---------------------------------------------------------------------------
__global__ __launch_bounds__(256) void gemm_zx_kernel(
    const float* __restrict__ x, const unsigned short* __restrict__ wT,
    const float* __restrict__ bias, unsigned short* __restrict__ zxp) {
  __shared__ __align__(16) unsigned short As[128][32];
  __shared__ __align__(16) unsigned short Bs[128][32];
  const int m0 = blockIdx.y * 128;
  const int n0 = blockIdx.x * 128;
  const int tid = threadIdx.x;
  const int wid = tid >> 6, lane = tid & 63;
  const int quad = lane >> 4, nl = lane & 15;
  const int wm = (wid & 1) * 64, wn = (wid >> 1) * 64;
  const int srow = tid >> 3;
  const int skk = (tid & 7) * 4;

  floatx4 acc[4][4] = {};

  for (int kt = 0; kt < 16; ++kt) {
    const int k0 = kt * 32;
    __syncthreads();
#pragma unroll
    for (int r = 0; r < 4; ++r) {
      const int row = r * 32 + srow;
      const float4 v =
          *reinterpret_cast<const float4*>(&x[(size_t)(m0 + row) * NI + k0 + skk]);
      *reinterpret_cast<ull_t*>(&As[row][skk]) = pack4bf(v.x, v.y, v.z, v.w);
      *reinterpret_cast<ull_t*>(&Bs[row][skk]) =
          *reinterpret_cast<const ull_t*>(&wT[(size_t)(n0 + row) * KTOT + k0 + skk]);
    }
    __syncthreads();
    bf16x8 af[4], bfr[4];
#pragma unroll
    for (int i = 0; i < 4; ++i) {
      af[i] = ldfrag(&As[wm + i * 16 + nl][quad * 8]);
      bfr[i] = ldfrag(&Bs[wn + i * 16 + nl][quad * 8]);
    }
#pragma unroll
    for (int i = 0; i < 4; ++i)
#pragma unroll
      for (int j = 0; j < 4; ++j)
        acc[i][j] =
            __builtin_amdgcn_mfma_f32_16x16x32_bf16(af[i], bfr[j], acc[i][j], 0, 0, 0);
  }

  float bv[4];
#pragma unroll
  for (int j = 0; j < 4; ++j) {
    const int colp = n0 + wn + j * 16 + nl;
    bv[j] = bias[(colp & 3) * 512 + (colp >> 2)];
  }
#pragma unroll
  for (int i = 0; i < 4; ++i) {
    const int browb = wm + i * 16 + quad * 4;
    const int t = (m0 + browb) >> 6;
    const int rt = (browb >> 5) & 1;
    const int hi = (browb & 31) >> 3;
    const int qb = (browb >> 2) & 1;
#pragma unroll
    for (int j = 0; j < 4; ++j) {
      const int colp = n0 + wn + j * 16 + nl;
      const int cbl = colp >> 5;
      const int lanep = (colp & 31) + 32 * qb;
      const ull_t packed =
          pack4bf(acc[i][j][0] + bv[j], acc[i][j][1] + bv[j],
                  acc[i][j][2] + bv[j], acc[i][j][3] + bv[j]);
      *reinterpret_cast<ull_t*>(
          &zxp[((((size_t)t * 64 + cbl) * 2 + rt) * 64 + lanep) * 16 + hi * 4]) = packed;
    }
  }
}

// ---------------------------------------------------------------------------
// recurrence: 256 blocks x 64 thr. Block (cb=bid>>2, qr=bid&3). Swapped MFMA
// (lane l15 = row, acc regs = gates), speculative MFMA + NaN-validate on acc.
// ---------------------------------------------------------------------------
__global__ __launch_bounds__(64) void lstm_rec_kernel(
    const unsigned short* __restrict__ zxp, const unsigned short* __restrict__ wT,
    const float* __restrict__ cs_init, float* __restrict__ out,
    unsigned short* __restrict__ hbf) {
  const int lane = threadIdx.x;
  const int bid = blockIdx.x;
  const int cb = bid >> 2;               // units [cb*8, +8), z-cols [cb*32,+32)
  const int qr = bid & 3;                // rows [qr*16, +16)
  const int l15 = lane & 15, quad = lane >> 4;
  const int row = qr * 16 + l15;         // this lane's batch row

  // A-operand resident: wT frags; lane m = l15 -> col cb*32 + cf*16 + l15,
  // k-slot = 512 + kf*32 + quad*8 + j (wT k>=512 is perm'd to match hbf).
  bf16x8 Wf[2][16];
#pragma unroll
  for (int cf = 0; cf < 2; ++cf)
#pragma unroll
    for (int kf = 0; kf < 16; ++kf)
      Wf[cf][kf] = ldfrag(
          &wT[(size_t)(cb * 32 + cf * 16 + l15) * KTOT + 512 + kf * 32 + quad * 8]);

  // cell state: (row, units cb*8+quad and cb*8+4+quad)
  float csv[2];
  csv[0] = cs_init[row * NU + cb * 8 + quad];
  csv[1] = cs_init[row * NU + cb * 8 + 4 + quad];

  // h fragment state (16 frags x 16B as lo/hi 8B atomic loads)
  ull_t AL[16], AH[16];
  auto issueA = [&](int tt) {
    const unsigned short* p0 =
        hbf + (size_t)tt * 32768 + (size_t)quad * 512 + (size_t)row * 8;
#pragma unroll
    for (int kf = 0; kf < 16; ++kf) {
      const unsigned short* p = p0 + (size_t)kf * 2048;
      AL[kf] = __hip_atomic_load((const ull_t*)p, __ATOMIC_RELAXED,
                                 __HIP_MEMORY_SCOPE_AGENT);
      AH[kf] = __hip_atomic_load((const ull_t*)(p + 4), __ATOMIC_RELAXED,
                                 __HIP_MEMORY_SCOPE_AGENT);
    }
  };

  // zx scalar preloads (gemm C-fragment layout), 8 x 2B, off critical path
  unsigned short zxv[8];
  const int rt_ = qr >> 1;
  const int qb_ = (l15 >> 2) & 1;
  const int hi_ = (qr & 1) * 2 + (l15 >> 3);
  const int rr_ = l15 & 3;
  auto issueZ = [&](int tt) {
    const size_t base = (((size_t)tt * 64 + cb) * 2 + rt_) * 64;
#pragma unroll
    for (int cf = 0; cf < 2; ++cf)
#pragma unroll
      for (int g = 0; g < 4; ++g) {
        const int c5 = cf * 16 + quad * 4 + g;
        zxv[cf * 4 + g] = zxp[(base + (size_t)(c5 + 32 * qb_)) * 16 + hi_ * 4 + rr_];
      }
  };

  issueA(0);
  issueZ(0);

  for (int t = 0; t < T_STEPS; ++t) {
    // ---- speculative MFMA + NaN-validate on acc; retry reloads + redoes ----
    floatx4 z0, z1;
    int tries = 0;
    while (true) {
      floatx4 p00 = {0.f, 0.f, 0.f, 0.f}, p01 = {0.f, 0.f, 0.f, 0.f};
      floatx4 p10 = {0.f, 0.f, 0.f, 0.f}, p11 = {0.f, 0.f, 0.f, 0.f};
#pragma unroll
      for (int kf = 0; kf < 8; ++kf) {
        const bf16x8 hlo = mkfrag(AL[kf], AH[kf]);
        const bf16x8 hhi = mkfrag(AL[8 + kf], AH[8 + kf]);
        p00 = __builtin_amdgcn_mfma_f32_16x16x32_bf16(Wf[0][kf], hlo, p00, 0, 0, 0);
        p01 = __builtin_amdgcn_mfma_f32_16x16x32_bf16(Wf[1][kf], hlo, p01, 0, 0, 0);
        p10 = __builtin_amdgcn_mfma_f32_16x16x32_bf16(Wf[0][8 + kf], hhi, p10, 0, 0, 0);
        p11 = __builtin_amdgcn_mfma_f32_16x16x32_bf16(Wf[1][8 + kf], hhi, p11, 0, 0, 0);
      }
      z0 = p00 + p10;  // unit cb*8+quad     : gates (i,ci,f,o) in regs
      z1 = p01 + p11;  // unit cb*8+4+quad   : gates (i,ci,f,o) in regs
      const float s = ((z0[0] + z0[1]) + (z0[2] + z0[3])) +
                      ((z1[0] + z1[1]) + (z1[2] + z1[3]));
      if (!__any(s != s) || ++tries >= (1 << 16)) break;  // poison -> NaN
      issueA(t);
    }

    // ---- gates directly on acc regs + zx scalars ----
    float hout[2];
    {
      const float iv = sigmoidf_(z0[0] + bf2f(zxv[0]));
      const float civ = fast_tanhf(z0[1] + bf2f(zxv[1]));
      const float fv = sigmoidf_(z0[2] + bf2f(zxv[2]) + 1.0f);  // forget_bias
      const float ov = sigmoidf_(z0[3] + bf2f(zxv[3]));
      csv[0] = civ * iv + csv[0] * fv;
      hout[0] = fast_tanhf(csv[0]) * ov;
    }
    {
      const float iv = sigmoidf_(z1[0] + bf2f(zxv[4]));
      const float civ = fast_tanhf(z1[1] + bf2f(zxv[5]));
      const float fv = sigmoidf_(z1[2] + bf2f(zxv[6]) + 1.0f);
      const float ov = sigmoidf_(z1[3] + bf2f(zxv[7]));
      csv[1] = civ * iv + csv[1] * fv;
      hout[1] = fast_tanhf(csv[1]) * ov;
    }

    // ---- h store: one 4B agent store per lane (units u, u+4 adjacent) ----
    unsigned short* hw = &hbf[(size_t)(t + 1) * 32768 + (size_t)(cb >> 2) * 2048 +
                              (size_t)(cb & 3) * 512 + (size_t)row * 8 + 2 * quad];
    const unsigned hv = (unsigned)f2bf(hout[0]) | ((unsigned)f2bf(hout[1]) << 16);
    __hip_atomic_store(reinterpret_cast<unsigned*>(hw), hv, __ATOMIC_RELAXED,
                       __HIP_MEMORY_SCOPE_AGENT);

    // ---- pre-issue next step's speculative loads (overlap gates/stores) ----
    if (t + 1 < T_STEPS) {
      issueA(t + 1);
      issueZ(t + 1);
    }

    // ---- out stores (off the critical path) ----
    float* op = &out[((size_t)t * NB + row) * NU + cb * 8];
    op[quad] = hout[0];
    op[4 + quad] = hout[1];
    if (t == T_STEPS - 1) {
      float* cp = &out[HSEQ_ELEMS + (size_t)row * NU + cb * 8];
      cp[quad] = csv[0];
      cp[4 + quad] = csv[1];
      float* hp2 = &out[HSEQ_ELEMS + NB * NU + (size_t)row * NU + cb * 8];
      hp2[quad] = hout[0];
      hp2[4 + quad] = hout[1];
    }
  }
}

// ---------------------------------------------------------------------------
extern "C" void kernel_launch(void* const* d_in, const int* in_sizes, int n_in,
                              void* d_out, int out_size, void* d_ws, size_t ws_size,
                              hipStream_t stream) {
  const float* x = (const float*)d_in[0];
  const float* cs0 = (const float*)d_in[1];
  const float* h0 = (const float*)d_in[2];
  const float* w = (const float*)d_in[3];
  const float* bias = (const float*)d_in[4];
  float* out = (float*)d_out;

  char* ws = (char*)d_ws;
  unsigned short* wT = (unsigned short*)(ws);
  unsigned short* zxp = (unsigned short*)(ws + (size_t)(4 << 20));
  unsigned short* hbf = (unsigned short*)(ws + (size_t)(132 << 20));

  init_kernel<<<dim3(2056), 256, 0, stream>>>(h0, hbf);
  transpose_w_kernel<<<dim3(16, 32, 4), 256, 0, stream>>>(w, wT);
  gemm_zx_kernel<<<dim3(16, 256), 256, 0, stream>>>(x, wT, bias, zxp);
  lstm_rec_kernel<<<dim3(256), 64, 0, stream>>>(zxp, wT, cs0, out, hbf);
}